// Round 1
// baseline (620.378 us; speedup 1.0000x reference)
//
#include <hip/hip_runtime.h>
#include <hip/hip_cooperative_groups.h>
#include <math.h>

namespace cg = cooperative_groups;

namespace {
constexpr int kTokens = 8192;
constexpr int kHS = 4096;
constexpr int kBlocks = 256;
constexpr int kRowsPerBlk = 32;
constexpr int kRowsPerWave = 8;
constexpr float kTol = 1e-4f;
constexpr float kEps = 1e-8f;
constexpr int kMaxIters = 1000;
}  // namespace

__device__ __forceinline__ float wave_sum(float v) {
#pragma unroll
  for (int o = 32; o; o >>= 1) v += __shfl_xor(v, o, 64);
  return v;
}

__global__ void __launch_bounds__(256, 1)
sinkhorn_router(const float* __restrict__ X, const float* __restrict__ W,
                float* __restrict__ out, float* __restrict__ ws) {
  cg::grid_group grid = cg::this_grid();
  const int tid = threadIdx.x;
  const int lane = tid & 63;
  const int wid = __builtin_amdgcn_readfirstlane(tid >> 6);
  const int blk = blockIdx.x;

  float4* wtp = reinterpret_cast<float4*>(ws);  // [1024*64] float4 = 1 MB
  float* gpart = ws + (size_t)4 * 1024 * 64;    // [2][256][64] floats = 128 KB
  __shared__ float lds[256];

  // ---- Phase 0: pack W^T as wtp[k4*64 + e] = W[e][4k4 .. 4k4+3] ----
  {
    const int j = blk * 256 + tid;  // 65536 float4s total
    const int e = j & 63;
    const int k4 = j >> 6;
    const float* src = W + (size_t)e * kHS + 4 * (size_t)k4;
    wtp[j] = make_float4(src[0], src[1], src[2], src[3]);
  }
  grid.sync();

  // ---- Phase 1: logits. lane = expert e; wave owns 8 token rows ----
  const int t0 = blk * kRowsPerBlk + wid * kRowsPerWave;  // wave-uniform
  const float* xb = X + (size_t)t0 * kHS;                 // uniform -> s_load
  float lg[kRowsPerWave];
#pragma unroll
  for (int t = 0; t < kRowsPerWave; ++t) lg[t] = 0.0f;

#pragma unroll 2
  for (int k4 = 0; k4 < kHS / 4; ++k4) {
    const float4 w = wtp[k4 * 64 + lane];  // coalesced 1 KB/wave, L2-hot
#pragma unroll
    for (int t = 0; t < kRowsPerWave; ++t) {
      const float* xr = xb + (size_t)t * kHS + 4 * (size_t)k4;  // uniform
      float a = lg[t];
      a = fmaf(xr[0], w.x, a);
      a = fmaf(xr[1], w.y, a);
      a = fmaf(xr[2], w.z, a);
      a = fmaf(xr[3], w.w, a);
      lg[t] = a;
    }
  }

  float cst[kRowsPerWave];
#pragma unroll
  for (int t = 0; t < kRowsPerWave; ++t) cst[t] = expf(lg[t]);

  // ---- Phase 2: sinkhorn. lane e holds d1[e]; one grid.sync per iter ----
  float d1 = 1.0f;
  float d0v[kRowsPerWave];
  int buf = 0;
  for (int it = 0; it < kMaxIters; ++it) {
    // row sums with current d1 -> d0 for this wave's rows; local col partials
    float p = 0.0f;
#pragma unroll
    for (int t = 0; t < kRowsPerWave; ++t) {
      const float s = wave_sum(d1 * cst[t]);
      const float d0t = (1.0f / 8192.0f) / (s + kEps);
      d0v[t] = d0t;
      p = fmaf(d0t, cst[t], p);
    }
    __syncthreads();  // prior iteration's lds reads are complete
    lds[wid * 64 + lane] = p;
    __syncthreads();
    if (wid == 0) {
      const float bp =
          lds[lane] + lds[64 + lane] + lds[128 + lane] + lds[192 + lane];
      gpart[buf * (kBlocks * 64) + blk * 64 + lane] = bp;
    }
    grid.sync();
    // every block redundantly reduces all 256 partials (identical order ->
    // bitwise-identical d1/err in all blocks -> uniform loop exit)
    const float* gp = gpart + buf * (kBlocks * 64);
    float s = 0.0f;
#pragma unroll 8
    for (int b = 0; b < 64; ++b) s += gp[(wid * 64 + b) * 64 + lane];
    lds[wid * 64 + lane] = s;  // safe: grid.sync included block barrier
    __syncthreads();
    const float colsum =
        lds[lane] + lds[64 + lane] + lds[128 + lane] + lds[192 + lane];
    const float d1n = (1.0f / 64.0f) / (colsum + kEps);
    const float err = wave_sum(fabsf(d1 - d1n)) * (1.0f / 64.0f);
    d1 = d1n;
    buf ^= 1;
    if (err <= kTol) break;
  }

  // ---- Phase 3: top-2 of d1*cost*d0 + softmax scores ----
#pragma unroll
  for (int t = 0; t < kRowsPerWave; ++t) {
    const float lgv = lg[t];
    // softmax over the row (loose tolerance, but do it right)
    float m = lgv;
#pragma unroll
    for (int o = 32; o; o >>= 1) m = fmaxf(m, __shfl_xor(m, o, 64));
    const float ex = expf(lgv - m);
    const float den = wave_sum(ex);
    const float prob = ex / den;

    const float v = (d1 * cst[t]) * d0v[t];
    // argmax #1 (ties -> lower index, matching lax.top_k)
    float v1 = v;
    int i1 = lane;
#pragma unroll
    for (int o = 32; o; o >>= 1) {
      const float ov = __shfl_xor(v1, o, 64);
      const int oi = __shfl_xor(i1, o, 64);
      if (ov > v1 || (ov == v1 && oi < i1)) { v1 = ov; i1 = oi; }
    }
    // argmax #2
    float v2 = (lane == i1) ? -INFINITY : v;
    int i2 = lane;
#pragma unroll
    for (int o = 32; o; o >>= 1) {
      const float ov = __shfl_xor(v2, o, 64);
      const int oi = __shfl_xor(i2, o, 64);
      if (ov > v2 || (ov == v2 && oi < i2)) { v2 = ov; i2 = oi; }
    }
    const float p1 = __shfl(prob, i1, 64);
    const float p2 = __shfl(prob, i2, 64);
    if (lane == 0) {
      const int row = t0 + t;
      out[row * 2 + 0] = p1;
      out[row * 2 + 1] = p2;
      out[2 * kTokens + row * 2 + 0] = (float)i1;
      out[2 * kTokens + row * 2 + 1] = (float)i2;
    }
  }
}

extern "C" void kernel_launch(void* const* d_in, const int* in_sizes, int n_in,
                              void* d_out, int out_size, void* d_ws,
                              size_t ws_size, hipStream_t stream) {
  const float* X = (const float*)d_in[0];
  const float* W = (const float*)d_in[1];
  float* out = (float*)d_out;
  float* ws = (float*)d_ws;
  void* args[] = {(void*)&X, (void*)&W, (void*)&out, (void*)&ws};
  hipLaunchCooperativeKernel((const void*)sinkhorn_router, dim3(kBlocks),
                             dim3(256), args, 0, stream);
}

// Round 2
// 573.391 us; speedup vs baseline: 1.0819x; 1.0819x over previous
//
#include <hip/hip_runtime.h>
#include <hip/hip_cooperative_groups.h>
#include <math.h>

namespace cg = cooperative_groups;

namespace {
constexpr int kTokens = 8192;
constexpr int kHS = 4096;
constexpr int kBlocks = 256;     // row-blocks; also coop grid size
constexpr int kRowsPerBlk = 32;
constexpr int kRowsPerWave = 8;
constexpr float kTol = 1e-4f;
constexpr float kEps = 1e-8f;
constexpr int kMaxIters = 1000;
constexpr size_t kWtpFloats = (size_t)(kHS / 4) * 64 * 4;  // 262144
constexpr size_t kSliceFloats = (size_t)kTokens * 64;      // 524288
constexpr size_t kGpartFloats = 2 * 256 * 64;              // 32768
}  // namespace

__device__ __forceinline__ float wave_sum(float v) {
#pragma unroll
  for (int o = 32; o; o >>= 1) v += __shfl_xor(v, o, 64);
  return v;
}

// ---------- K0: pack W^T as wtp[k4*64 + e] = W[e][4k4..4k4+3] ----------
__global__ void __launch_bounds__(256) k_pack(const float* __restrict__ W,
                                              float4* __restrict__ wtp) {
  const int j = blockIdx.x * 256 + threadIdx.x;  // 65536 float4s
  const int e = j & 63;
  const int k4 = j >> 6;
  wtp[j] = *reinterpret_cast<const float4*>(W + (size_t)e * kHS + 4 * (size_t)k4);
}

// ---------- K1: split-K logits partials. grid = 256*S blocks ----------
__global__ void __launch_bounds__(256) k_logits(const float* __restrict__ X,
                                                const float4* __restrict__ wtp,
                                                float* __restrict__ part,
                                                int K4S) {
  const int tid = threadIdx.x;
  const int lane = tid & 63;
  const int wid = __builtin_amdgcn_readfirstlane(tid >> 6);
  const int sb = blockIdx.x & 255;  // row-block
  const int s = blockIdx.x >> 8;    // k-slice
  const int t0 = sb * kRowsPerBlk + wid * kRowsPerWave;  // wave-uniform
  const int k40 = s * K4S;
  const float* xb = X + (size_t)t0 * kHS + 4 * (size_t)k40;  // uniform -> s_load
  float acc[kRowsPerWave];
#pragma unroll
  for (int t = 0; t < kRowsPerWave; ++t) acc[t] = 0.0f;

#pragma unroll 2
  for (int k4 = 0; k4 < K4S; ++k4) {
    const float4 w = wtp[(size_t)(k40 + k4) * 64 + lane];  // coalesced, L2-hot
#pragma unroll
    for (int t = 0; t < kRowsPerWave; ++t) {
      const float* xr = xb + (size_t)t * kHS + 4 * (size_t)k4;  // uniform
      float a = acc[t];
      a = fmaf(xr[0], w.x, a);
      a = fmaf(xr[1], w.y, a);
      a = fmaf(xr[2], w.z, a);
      a = fmaf(xr[3], w.w, a);
      acc[t] = a;
    }
  }
  float* pb = part + ((size_t)s * kTokens + t0) * 64;
#pragma unroll
  for (int t = 0; t < kRowsPerWave; ++t) pb[(size_t)t * 64 + lane] = acc[t];
}

// ---------- K2: cooperative sinkhorn + top-2 + softmax ----------
__global__ void __launch_bounds__(256, 1)
k_sinkhorn(const float* __restrict__ part, int S, float* __restrict__ out,
           float* __restrict__ gpart) {
  cg::grid_group grid = cg::this_grid();
  const int tid = threadIdx.x;
  const int lane = tid & 63;
  const int wid = __builtin_amdgcn_readfirstlane(tid >> 6);
  const int blk = blockIdx.x;
  __shared__ float lds[256];

  const int t0 = blk * kRowsPerBlk + wid * kRowsPerWave;
  float lg[kRowsPerWave], cst[kRowsPerWave];
#pragma unroll
  for (int t = 0; t < kRowsPerWave; ++t) {
    float a = 0.0f;
    for (int s = 0; s < S; ++s)
      a += part[((size_t)s * kTokens + t0 + t) * 64 + lane];
    lg[t] = a;
    cst[t] = expf(a);
  }

  // sinkhorn: lane e holds d1[e]; one grid.sync per iteration
  float d1 = 1.0f;
  float d0v[kRowsPerWave];
  int buf = 0;
  for (int it = 0; it < kMaxIters; ++it) {
    float p = 0.0f;
#pragma unroll
    for (int t = 0; t < kRowsPerWave; ++t) {
      const float s = wave_sum(d1 * cst[t]);
      const float d0t = (1.0f / 8192.0f) / (s + kEps);
      d0v[t] = d0t;
      p = fmaf(d0t, cst[t], p);
    }
    __syncthreads();
    lds[wid * 64 + lane] = p;
    __syncthreads();
    if (wid == 0) {
      const float bp =
          lds[lane] + lds[64 + lane] + lds[128 + lane] + lds[192 + lane];
      gpart[buf * (kBlocks * 64) + blk * 64 + lane] = bp;
    }
    grid.sync();
    // every block redundantly reduces all 256 partials (identical order ->
    // bitwise-identical d1/err in all blocks -> uniform loop exit)
    const float* gp = gpart + buf * (kBlocks * 64);
    float s = 0.0f;
#pragma unroll 8
    for (int b = 0; b < 64; ++b) s += gp[(wid * 64 + b) * 64 + lane];
    lds[wid * 64 + lane] = s;
    __syncthreads();
    const float colsum =
        lds[lane] + lds[64 + lane] + lds[128 + lane] + lds[192 + lane];
    const float d1n = (1.0f / 64.0f) / (colsum + kEps);
    const float err = wave_sum(fabsf(d1 - d1n)) * (1.0f / 64.0f);
    d1 = d1n;
    buf ^= 1;
    if (err <= kTol) break;
  }

  // top-2 of d1*cost*d0 + softmax scores
#pragma unroll
  for (int t = 0; t < kRowsPerWave; ++t) {
    const float lgv = lg[t];
    float m = lgv;
#pragma unroll
    for (int o = 32; o; o >>= 1) m = fmaxf(m, __shfl_xor(m, o, 64));
    const float ex = expf(lgv - m);
    const float den = wave_sum(ex);
    const float prob = ex / den;

    const float v = (d1 * cst[t]) * d0v[t];
    float v1 = v;
    int i1 = lane;
#pragma unroll
    for (int o = 32; o; o >>= 1) {
      const float ov = __shfl_xor(v1, o, 64);
      const int oi = __shfl_xor(i1, o, 64);
      if (ov > v1 || (ov == v1 && oi < i1)) { v1 = ov; i1 = oi; }
    }
    float v2 = (lane == i1) ? -INFINITY : v;
    int i2 = lane;
#pragma unroll
    for (int o = 32; o; o >>= 1) {
      const float ov = __shfl_xor(v2, o, 64);
      const int oi = __shfl_xor(i2, o, 64);
      if (ov > v2 || (ov == v2 && oi < i2)) { v2 = ov; i2 = oi; }
    }
    const float p1 = __shfl(prob, i1, 64);
    const float p2 = __shfl(prob, i2, 64);
    if (lane == 0) {
      const int row = t0 + t;
      out[row * 2 + 0] = p1;
      out[row * 2 + 1] = p2;
      out[2 * kTokens + row * 2 + 0] = (float)i1;
      out[2 * kTokens + row * 2 + 1] = (float)i2;
    }
  }
}

// ---------- fallback: round-1 monolithic cooperative kernel ----------
__global__ void __launch_bounds__(256, 1)
sinkhorn_router(const float* __restrict__ X, const float* __restrict__ W,
                float* __restrict__ out, float* __restrict__ ws) {
  cg::grid_group grid = cg::this_grid();
  const int tid = threadIdx.x;
  const int lane = tid & 63;
  const int wid = __builtin_amdgcn_readfirstlane(tid >> 6);
  const int blk = blockIdx.x;

  float4* wtp = reinterpret_cast<float4*>(ws);
  float* gpart = ws + kWtpFloats;
  __shared__ float lds[256];

  {
    const int j = blk * 256 + tid;
    const int e = j & 63;
    const int k4 = j >> 6;
    wtp[j] = *reinterpret_cast<const float4*>(W + (size_t)e * kHS + 4 * (size_t)k4);
  }
  grid.sync();

  const int t0 = blk * kRowsPerBlk + wid * kRowsPerWave;
  const float* xb = X + (size_t)t0 * kHS;
  float lg[kRowsPerWave];
#pragma unroll
  for (int t = 0; t < kRowsPerWave; ++t) lg[t] = 0.0f;

#pragma unroll 2
  for (int k4 = 0; k4 < kHS / 4; ++k4) {
    const float4 w = wtp[k4 * 64 + lane];
#pragma unroll
    for (int t = 0; t < kRowsPerWave; ++t) {
      const float* xr = xb + (size_t)t * kHS + 4 * (size_t)k4;
      float a = lg[t];
      a = fmaf(xr[0], w.x, a);
      a = fmaf(xr[1], w.y, a);
      a = fmaf(xr[2], w.z, a);
      a = fmaf(xr[3], w.w, a);
      lg[t] = a;
    }
  }

  float cst[kRowsPerWave];
#pragma unroll
  for (int t = 0; t < kRowsPerWave; ++t) cst[t] = expf(lg[t]);

  float d1 = 1.0f;
  float d0v[kRowsPerWave];
  int buf = 0;
  for (int it = 0; it < kMaxIters; ++it) {
    float p = 0.0f;
#pragma unroll
    for (int t = 0; t < kRowsPerWave; ++t) {
      const float s = wave_sum(d1 * cst[t]);
      const float d0t = (1.0f / 8192.0f) / (s + kEps);
      d0v[t] = d0t;
      p = fmaf(d0t, cst[t], p);
    }
    __syncthreads();
    lds[wid * 64 + lane] = p;
    __syncthreads();
    if (wid == 0) {
      const float bp =
          lds[lane] + lds[64 + lane] + lds[128 + lane] + lds[192 + lane];
      gpart[buf * (kBlocks * 64) + blk * 64 + lane] = bp;
    }
    grid.sync();
    const float* gp = gpart + buf * (kBlocks * 64);
    float s = 0.0f;
#pragma unroll 8
    for (int b = 0; b < 64; ++b) s += gp[(wid * 64 + b) * 64 + lane];
    lds[wid * 64 + lane] = s;
    __syncthreads();
    const float colsum =
        lds[lane] + lds[64 + lane] + lds[128 + lane] + lds[192 + lane];
    const float d1n = (1.0f / 64.0f) / (colsum + kEps);
    const float err = wave_sum(fabsf(d1 - d1n)) * (1.0f / 64.0f);
    d1 = d1n;
    buf ^= 1;
    if (err <= kTol) break;
  }

#pragma unroll
  for (int t = 0; t < kRowsPerWave; ++t) {
    const float lgv = lg[t];
    float m = lgv;
#pragma unroll
    for (int o = 32; o; o >>= 1) m = fmaxf(m, __shfl_xor(m, o, 64));
    const float ex = expf(lgv - m);
    const float den = wave_sum(ex);
    const float prob = ex / den;

    const float v = (d1 * cst[t]) * d0v[t];
    float v1 = v;
    int i1 = lane;
#pragma unroll
    for (int o = 32; o; o >>= 1) {
      const float ov = __shfl_xor(v1, o, 64);
      const int oi = __shfl_xor(i1, o, 64);
      if (ov > v1 || (ov == v1 && oi < i1)) { v1 = ov; i1 = oi; }
    }
    float v2 = (lane == i1) ? -INFINITY : v;
    int i2 = lane;
#pragma unroll
    for (int o = 32; o; o >>= 1) {
      const float ov = __shfl_xor(v2, o, 64);
      const int oi = __shfl_xor(i2, o, 64);
      if (ov > v2 || (ov == v2 && oi < i2)) { v2 = ov; i2 = oi; }
    }
    const float p1 = __shfl(prob, i1, 64);
    const float p2 = __shfl(prob, i2, 64);
    if (lane == 0) {
      const int row = t0 + t;
      out[row * 2 + 0] = p1;
      out[row * 2 + 1] = p2;
      out[2 * kTokens + row * 2 + 0] = (float)i1;
      out[2 * kTokens + row * 2 + 1] = (float)i2;
    }
  }
}

extern "C" void kernel_launch(void* const* d_in, const int* in_sizes, int n_in,
                              void* d_out, int out_size, void* d_ws,
                              size_t ws_size, hipStream_t stream) {
  const float* X = (const float*)d_in[0];
  const float* W = (const float*)d_in[1];
  float* out = (float*)d_out;
  float* ws = (float*)d_ws;

  // pick largest split-K S in {8,4,2,1} that fits ws
  int S = 0;
  for (int cand : {8, 4, 2, 1}) {
    const size_t need =
        (kWtpFloats + (size_t)cand * kSliceFloats + kGpartFloats) * 4;
    if (need <= ws_size) { S = cand; break; }
  }

  if (S == 0) {
    // fallback: round-1 monolithic path (needs only ~1.2 MB of ws)
    void* args[] = {(void*)&X, (void*)&W, (void*)&out, (void*)&ws};
    hipLaunchCooperativeKernel((const void*)sinkhorn_router, dim3(kBlocks),
                               dim3(256), args, 0, stream);
    return;
  }

  float4* wtp = reinterpret_cast<float4*>(ws);
  float* part = ws + kWtpFloats;
  float* gpart = part + (size_t)S * kSliceFloats;

  hipLaunchKernelGGL(k_pack, dim3(256), dim3(256), 0, stream, W, wtp);

  const int K4S = (kHS / 4) / S;
  hipLaunchKernelGGL(k_logits, dim3(256 * S), dim3(256), 0, stream, X,
                     (const float4*)wtp, part, K4S);

  const float* partc = part;
  void* args[] = {(void*)&partc, (void*)&S, (void*)&out, (void*)&gpart};
  hipLaunchCooperativeKernel((const void*)k_sinkhorn, dim3(kBlocks), dim3(256),
                             args, 0, stream);
}

// Round 3
// 334.829 us; speedup vs baseline: 1.8528x; 1.7125x over previous
//
#include <hip/hip_runtime.h>
#include <hip/hip_cooperative_groups.h>
#include <math.h>

namespace cg = cooperative_groups;

namespace {
constexpr int kTokens = 8192;
constexpr int kHS = 4096;
constexpr float kTol = 1e-4f;
constexpr float kEps = 1e-8f;
constexpr int kMaxIters = 1000;
constexpr int kSinkBlocks = 64;    // fewer coop blocks -> cheaper grid.sync
constexpr size_t kWtpFloats = (size_t)(kHS / 4) * 64 * 4;  // 262144
constexpr size_t kSliceFloats = (size_t)kTokens * 64;      // 524288
constexpr size_t kGpartFloats = 2 * 256 * 64;              // (sized generously)
}  // namespace

__device__ __forceinline__ float wave_sum(float v) {
#pragma unroll
  for (int o = 32; o; o >>= 1) v += __shfl_xor(v, o, 64);
  return v;
}

// broadcast lane src's value to all lanes via VALU readlane (not LDS pipe)
__device__ __forceinline__ float bcast(float v, int src) {
  return __uint_as_float(__builtin_amdgcn_readlane(__float_as_uint(v), src));
}

// ---------- K0: pack W^T as wtp[k4*64 + e] = W[e][4k4..4k4+3] ----------
__global__ void __launch_bounds__(256) k_pack(const float* __restrict__ W,
                                              float4* __restrict__ wtp) {
  const int j = blockIdx.x * 256 + threadIdx.x;  // 65536 float4s
  const int e = j & 63;
  const int k4 = j >> 6;
  wtp[j] = *reinterpret_cast<const float4*>(W + (size_t)e * kHS + 4 * (size_t)k4);
}

// ---------- K1: split-K logits partials, vector X + readlane bcast ----------
// grid = 256*S blocks; wave: lane=expert, 8 token rows; X loaded per-lane
// (row = lane>>3, k4 chunk = lane&7) then broadcast via v_readlane -> SGPR
// operand of v_fma. Accumulation order over k identical to prior rounds.
__global__ void __launch_bounds__(256, 8)
k_logits(const float4* __restrict__ X4, const float4* __restrict__ wtp,
         float* __restrict__ part, int K4S) {
  const int tid = threadIdx.x;
  const int lane = tid & 63;
  const int wid = tid >> 6;
  const int sb = blockIdx.x & 255;  // row-block
  const int s = blockIdx.x >> 8;    // k-slice
  const int t0 = sb * 32 + wid * 8;
  const int k40 = s * K4S;
  const int rhat = lane >> 3;  // row this lane loads X for
  const int jhat = lane & 7;   // k4 sub-chunk this lane loads
  const float4* xp = X4 + (size_t)(t0 + rhat) * (kHS / 4) + k40 + jhat;
  const float4* wp = wtp + (size_t)k40 * 64 + lane;

  float acc[8];
#pragma unroll
  for (int r = 0; r < 8; ++r) acc[r] = 0.0f;

  const int nOuter = K4S / 8;
  for (int ko = 0; ko < nOuter; ++ko) {
    const float4 xv = xp[(size_t)ko * 8];  // 8 rows x 8 k4 per wave-load
#pragma unroll
    for (int jj = 0; jj < 8; ++jj) {
      const float4 w = wp[(size_t)(ko * 8 + jj) * 64];
#pragma unroll
      for (int r = 0; r < 8; ++r) {
        const int src = r * 8 + jj;
        float a = acc[r];
        a = fmaf(bcast(xv.x, src), w.x, a);
        a = fmaf(bcast(xv.y, src), w.y, a);
        a = fmaf(bcast(xv.z, src), w.z, a);
        a = fmaf(bcast(xv.w, src), w.w, a);
        acc[r] = a;
      }
    }
  }
  float* pb = part + ((size_t)s * kTokens + t0) * 64;
#pragma unroll
  for (int r = 0; r < 8; ++r) pb[(size_t)r * 64 + lane] = acc[r];
}

// ---------- K2: cooperative sinkhorn + top-2 + softmax (64 blocks) ----------
__global__ void __launch_bounds__(1024, 1)
k_sinkhorn(const float* __restrict__ part, int S, float* __restrict__ out,
           float* __restrict__ gpart) {
  cg::grid_group grid = cg::this_grid();
  const int tid = threadIdx.x;
  const int lane = tid & 63;
  const int wid = __builtin_amdgcn_readfirstlane(tid >> 6);  // 0..15
  const int blk = blockIdx.x;                                // 0..63
  __shared__ float lds[1024];

  const int t0 = blk * 128 + wid * 8;
  float lg[8], cst[8];
#pragma unroll
  for (int t = 0; t < 8; ++t) {
    float a = 0.0f;
    for (int s = 0; s < S; ++s)
      a += part[((size_t)s * kTokens + t0 + t) * 64 + lane];
    lg[t] = a;
    cst[t] = expf(a);
  }

  // lane e holds d1[e]; one grid.sync per iteration
  float d1 = 1.0f;
  float d0v[8];
  int buf = 0;
  for (int it = 0; it < kMaxIters; ++it) {
    float p = 0.0f;
#pragma unroll
    for (int t = 0; t < 8; ++t) {
      const float s = wave_sum(d1 * cst[t]);
      const float d0t = (1.0f / 8192.0f) / (s + kEps);
      d0v[t] = d0t;
      p = fmaf(d0t, cst[t], p);
    }
    __syncthreads();
    lds[wid * 64 + lane] = p;
    __syncthreads();
    if (wid == 0) {
      float bp = 0.0f;
#pragma unroll
      for (int w = 0; w < 16; ++w) bp += lds[w * 64 + lane];
      gpart[buf * (kSinkBlocks * 64) + blk * 64 + lane] = bp;
    }
    grid.sync();
    // every block redundantly reduces all 64 partials in identical order ->
    // bitwise-identical d1/err in all blocks -> uniform loop exit
    const float* gp = gpart + buf * (kSinkBlocks * 64);
    float s2 = 0.0f;
#pragma unroll
    for (int i = 0; i < 4; ++i) s2 += gp[(wid * 4 + i) * 64 + lane];
    lds[wid * 64 + lane] = s2;
    __syncthreads();
    float colsum = 0.0f;
#pragma unroll
    for (int w = 0; w < 16; ++w) colsum += lds[w * 64 + lane];
    const float d1n = (1.0f / 64.0f) / (colsum + kEps);
    const float err = wave_sum(fabsf(d1 - d1n)) * (1.0f / 64.0f);
    d1 = d1n;
    buf ^= 1;
    if (err <= kTol) break;
  }

  // top-2 of d1*cost*d0 + softmax scores
#pragma unroll
  for (int t = 0; t < 8; ++t) {
    const float lgv = lg[t];
    float m = lgv;
#pragma unroll
    for (int o = 32; o; o >>= 1) m = fmaxf(m, __shfl_xor(m, o, 64));
    const float ex = expf(lgv - m);
    const float den = wave_sum(ex);
    const float prob = ex / den;

    const float v = (d1 * cst[t]) * d0v[t];
    float v1 = v;
    int i1 = lane;
#pragma unroll
    for (int o = 32; o; o >>= 1) {
      const float ov = __shfl_xor(v1, o, 64);
      const int oi = __shfl_xor(i1, o, 64);
      if (ov > v1 || (ov == v1 && oi < i1)) { v1 = ov; i1 = oi; }
    }
    float v2 = (lane == i1) ? -INFINITY : v;
    int i2 = lane;
#pragma unroll
    for (int o = 32; o; o >>= 1) {
      const float ov = __shfl_xor(v2, o, 64);
      const int oi = __shfl_xor(i2, o, 64);
      if (ov > v2 || (ov == v2 && oi < i2)) { v2 = ov; i2 = oi; }
    }
    const float p1 = __shfl(prob, i1, 64);
    const float p2 = __shfl(prob, i2, 64);
    if (lane == 0) {
      const int row = t0 + t;
      out[row * 2 + 0] = p1;
      out[row * 2 + 1] = p2;
      out[2 * kTokens + row * 2 + 0] = (float)i1;
      out[2 * kTokens + row * 2 + 1] = (float)i2;
    }
  }
}

// ---------- fallback: round-1 monolithic cooperative kernel ----------
__global__ void __launch_bounds__(256, 1)
sinkhorn_router(const float* __restrict__ X, const float* __restrict__ W,
                float* __restrict__ out, float* __restrict__ ws) {
  cg::grid_group grid = cg::this_grid();
  const int tid = threadIdx.x;
  const int lane = tid & 63;
  const int wid = __builtin_amdgcn_readfirstlane(tid >> 6);
  const int blk = blockIdx.x;

  float4* wtp = reinterpret_cast<float4*>(ws);
  float* gpart = ws + kWtpFloats;
  __shared__ float lds[256];

  {
    const int j = blk * 256 + tid;
    const int e = j & 63;
    const int k4 = j >> 6;
    wtp[j] = *reinterpret_cast<const float4*>(W + (size_t)e * kHS + 4 * (size_t)k4);
  }
  grid.sync();

  const int t0 = blk * 32 + wid * 8;
  const float* xb = X + (size_t)t0 * kHS;
  float lg[8];
#pragma unroll
  for (int t = 0; t < 8; ++t) lg[t] = 0.0f;

#pragma unroll 2
  for (int k4 = 0; k4 < kHS / 4; ++k4) {
    const float4 w = wtp[k4 * 64 + lane];
#pragma unroll
    for (int t = 0; t < 8; ++t) {
      const float* xr = xb + (size_t)t * kHS + 4 * (size_t)k4;
      float a = lg[t];
      a = fmaf(xr[0], w.x, a);
      a = fmaf(xr[1], w.y, a);
      a = fmaf(xr[2], w.z, a);
      a = fmaf(xr[3], w.w, a);
      lg[t] = a;
    }
  }

  float cst[8];
#pragma unroll
  for (int t = 0; t < 8; ++t) cst[t] = expf(lg[t]);

  float d1 = 1.0f;
  float d0v[8];
  int buf = 0;
  for (int it = 0; it < kMaxIters; ++it) {
    float p = 0.0f;
#pragma unroll
    for (int t = 0; t < 8; ++t) {
      const float s = wave_sum(d1 * cst[t]);
      const float d0t = (1.0f / 8192.0f) / (s + kEps);
      d0v[t] = d0t;
      p = fmaf(d0t, cst[t], p);
    }
    __syncthreads();
    lds[wid * 64 + lane] = p;
    __syncthreads();
    if (wid == 0) {
      const float bp =
          lds[lane] + lds[64 + lane] + lds[128 + lane] + lds[192 + lane];
      gpart[buf * (256 * 64) + blk * 64 + lane] = bp;
    }
    grid.sync();
    const float* gp = gpart + buf * (256 * 64);
    float s = 0.0f;
#pragma unroll 8
    for (int b = 0; b < 64; ++b) s += gp[(wid * 64 + b) * 64 + lane];
    lds[wid * 64 + lane] = s;
    __syncthreads();
    const float colsum =
        lds[lane] + lds[64 + lane] + lds[128 + lane] + lds[192 + lane];
    const float d1n = (1.0f / 64.0f) / (colsum + kEps);
    const float err = wave_sum(fabsf(d1 - d1n)) * (1.0f / 64.0f);
    d1 = d1n;
    buf ^= 1;
    if (err <= kTol) break;
  }

#pragma unroll
  for (int t = 0; t < 8; ++t) {
    const float lgv = lg[t];
    float m = lgv;
#pragma unroll
    for (int o = 32; o; o >>= 1) m = fmaxf(m, __shfl_xor(m, o, 64));
    const float ex = expf(lgv - m);
    const float den = wave_sum(ex);
    const float prob = ex / den;

    const float v = (d1 * cst[t]) * d0v[t];
    float v1 = v;
    int i1 = lane;
#pragma unroll
    for (int o = 32; o; o >>= 1) {
      const float ov = __shfl_xor(v1, o, 64);
      const int oi = __shfl_xor(i1, o, 64);
      if (ov > v1 || (ov == v1 && oi < i1)) { v1 = ov; i1 = oi; }
    }
    float v2 = (lane == i1) ? -INFINITY : v;
    int i2 = lane;
#pragma unroll
    for (int o = 32; o; o >>= 1) {
      const float ov = __shfl_xor(v2, o, 64);
      const int oi = __shfl_xor(i2, o, 64);
      if (ov > v2 || (ov == v2 && oi < i2)) { v2 = ov; i2 = oi; }
    }
    const float p1 = __shfl(prob, i1, 64);
    const float p2 = __shfl(prob, i2, 64);
    if (lane == 0) {
      const int row = t0 + t;
      out[row * 2 + 0] = p1;
      out[row * 2 + 1] = p2;
      out[2 * kTokens + row * 2 + 0] = (float)i1;
      out[2 * kTokens + row * 2 + 1] = (float)i2;
    }
  }
}

extern "C" void kernel_launch(void* const* d_in, const int* in_sizes, int n_in,
                              void* d_out, int out_size, void* d_ws,
                              size_t ws_size, hipStream_t stream) {
  const float* X = (const float*)d_in[0];
  const float* W = (const float*)d_in[1];
  float* out = (float*)d_out;
  float* ws = (float*)d_ws;

  // pick largest split-K S in {8,4,2,1} that fits ws
  int S = 0;
  for (int cand : {8, 4, 2, 1}) {
    const size_t need =
        (kWtpFloats + (size_t)cand * kSliceFloats + kGpartFloats) * 4;
    if (need <= ws_size) { S = cand; break; }
  }

  if (S == 0) {
    void* args[] = {(void*)&X, (void*)&W, (void*)&out, (void*)&ws};
    hipLaunchCooperativeKernel((const void*)sinkhorn_router, dim3(256),
                               dim3(256), args, 0, stream);
    return;
  }

  float4* wtp = reinterpret_cast<float4*>(ws);
  float* part = ws + kWtpFloats;
  float* gpart = part + (size_t)S * kSliceFloats;

  hipLaunchKernelGGL(k_pack, dim3(256), dim3(256), 0, stream, W, wtp);

  const int K4S = (kHS / 4) / S;
  hipLaunchKernelGGL(k_logits, dim3(256 * S), dim3(256), 0, stream,
                     (const float4*)X, (const float4*)wtp, part, K4S);

  const float* partc = part;
  void* args[] = {(void*)&partc, (void*)&S, (void*)&out, (void*)&gpart};
  hipLaunchCooperativeKernel((const void*)k_sinkhorn, dim3(kSinkBlocks),
                             dim3(1024), args, 0, stream);
}

// Round 4
// 301.215 us; speedup vs baseline: 2.0596x; 1.1116x over previous
//
#include <hip/hip_runtime.h>
#include <hip/hip_cooperative_groups.h>
#include <math.h>

namespace cg = cooperative_groups;

namespace {
constexpr int kTokens = 8192;
constexpr int kHS = 4096;
constexpr float kTol = 1e-4f;
constexpr float kEps = 1e-8f;
constexpr int kMaxIters = 1000;
constexpr int kSinkBlocks = 64;    // coop grid for sinkhorn
constexpr size_t kSliceFloats = (size_t)kTokens * 64;      // 524288
constexpr size_t kGpartFloats = 2 * 256 * 64;
constexpr size_t kWtpFloats = (size_t)(kHS / 4) * 64 * 4;  // fallback only
}  // namespace

__device__ __forceinline__ float wave_sum(float v) {
#pragma unroll
  for (int o = 32; o; o >>= 1) v += __shfl_xor(v, o, 64);
  return v;
}

// ---------- K1: split-K SGEMM logits. grid = 128*S blocks ----------
// Block tile: 64 tokens x 64 experts x (kHS/S). 256 threads, 4x4 per thread.
// X and W staged to LDS transposed [k][row(+4 pad)] so compute reads are
// ds_read_b128 along rows. 16 FMA per 2 LDS reads -> ~1.1 VALU inst/FMA.
__global__ void __launch_bounds__(256, 4)
k_logits(const float* __restrict__ X, const float* __restrict__ W,
         float* __restrict__ part, int KS) {
  __shared__ float xs[32][68];
  __shared__ float wsh[32][68];
  const int tid = threadIdx.x;
  const int tx = tid & 15;   // expert group: 4*tx..4*tx+3
  const int ty = tid >> 4;   // token group: 4*ty..4*ty+3
  const int nb = blockIdx.x & 127;  // token block
  const int s = blockIdx.x >> 7;    // k-slice
  const int t0 = nb * 64;
  const int k0 = s * KS;
  const int rr = tid >> 3;  // staging row 0..31 (and +32)
  const int jj = tid & 7;   // staging k-chunk (16B) within 128B row chunk
  const float* xp0 = X + (size_t)(t0 + rr) * kHS + k0 + 4 * jj;
  const float* xp1 = xp0 + (size_t)32 * kHS;
  const float* wp0 = W + (size_t)rr * kHS + k0 + 4 * jj;
  const float* wp1 = wp0 + (size_t)32 * kHS;

  float acc[4][4];
#pragma unroll
  for (int i = 0; i < 4; ++i)
#pragma unroll
    for (int j = 0; j < 4; ++j) acc[i][j] = 0.0f;

  const int nt = KS / 32;
  float4 xa = *(const float4*)xp0;
  float4 xb = *(const float4*)xp1;
  float4 wa = *(const float4*)wp0;
  float4 wb = *(const float4*)wp1;

  for (int kt = 0; kt < nt; ++kt) {
    __syncthreads();
    const int kk = 4 * jj;
    xs[kk + 0][rr] = xa.x;
    xs[kk + 1][rr] = xa.y;
    xs[kk + 2][rr] = xa.z;
    xs[kk + 3][rr] = xa.w;
    xs[kk + 0][rr + 32] = xb.x;
    xs[kk + 1][rr + 32] = xb.y;
    xs[kk + 2][rr + 32] = xb.z;
    xs[kk + 3][rr + 32] = xb.w;
    wsh[kk + 0][rr] = wa.x;
    wsh[kk + 1][rr] = wa.y;
    wsh[kk + 2][rr] = wa.z;
    wsh[kk + 3][rr] = wa.w;
    wsh[kk + 0][rr + 32] = wb.x;
    wsh[kk + 1][rr + 32] = wb.y;
    wsh[kk + 2][rr + 32] = wb.z;
    wsh[kk + 3][rr + 32] = wb.w;
    __syncthreads();
    if (kt + 1 < nt) {  // prefetch next tile while computing this one
      xa = *(const float4*)(xp0 + (kt + 1) * 32);
      xb = *(const float4*)(xp1 + (kt + 1) * 32);
      wa = *(const float4*)(wp0 + (kt + 1) * 32);
      wb = *(const float4*)(wp1 + (kt + 1) * 32);
    }
#pragma unroll
    for (int k = 0; k < 32; ++k) {
      const float4 xv = *(const float4*)&xs[k][4 * ty];
      const float4 wv = *(const float4*)&wsh[k][4 * tx];
      acc[0][0] = fmaf(xv.x, wv.x, acc[0][0]);
      acc[0][1] = fmaf(xv.x, wv.y, acc[0][1]);
      acc[0][2] = fmaf(xv.x, wv.z, acc[0][2]);
      acc[0][3] = fmaf(xv.x, wv.w, acc[0][3]);
      acc[1][0] = fmaf(xv.y, wv.x, acc[1][0]);
      acc[1][1] = fmaf(xv.y, wv.y, acc[1][1]);
      acc[1][2] = fmaf(xv.y, wv.z, acc[1][2]);
      acc[1][3] = fmaf(xv.y, wv.w, acc[1][3]);
      acc[2][0] = fmaf(xv.z, wv.x, acc[2][0]);
      acc[2][1] = fmaf(xv.z, wv.y, acc[2][1]);
      acc[2][2] = fmaf(xv.z, wv.z, acc[2][2]);
      acc[2][3] = fmaf(xv.z, wv.w, acc[2][3]);
      acc[3][0] = fmaf(xv.w, wv.x, acc[3][0]);
      acc[3][1] = fmaf(xv.w, wv.y, acc[3][1]);
      acc[3][2] = fmaf(xv.w, wv.z, acc[3][2]);
      acc[3][3] = fmaf(xv.w, wv.w, acc[3][3]);
    }
  }

  float* pb = part + ((size_t)s * kTokens + t0 + 4 * ty) * 64 + 4 * tx;
#pragma unroll
  for (int i = 0; i < 4; ++i)
    *(float4*)(pb + (size_t)i * 64) =
        make_float4(acc[i][0], acc[i][1], acc[i][2], acc[i][3]);
}

// ---------- K2: cooperative sinkhorn + top-2 + softmax (64 blocks) ----------
__global__ void __launch_bounds__(1024, 1)
k_sinkhorn(const float* __restrict__ part, int S, float* __restrict__ out,
           float* __restrict__ gpart) {
  cg::grid_group grid = cg::this_grid();
  const int tid = threadIdx.x;
  const int lane = tid & 63;
  const int wid = __builtin_amdgcn_readfirstlane(tid >> 6);  // 0..15
  const int blk = blockIdx.x;                                // 0..63
  __shared__ float lds[1024];

  const int t0 = blk * 128 + wid * 8;
  float lg[8], cst[8];
#pragma unroll
  for (int t = 0; t < 8; ++t) {
    float a = 0.0f;
    for (int s = 0; s < S; ++s)
      a += part[((size_t)s * kTokens + t0 + t) * 64 + lane];
    lg[t] = a;
    cst[t] = expf(a);
  }

  // lane e holds d1[e]; one grid.sync per iteration
  float d1 = 1.0f;
  float d0v[8];
  int buf = 0;
  for (int it = 0; it < kMaxIters; ++it) {
    float p = 0.0f;
#pragma unroll
    for (int t = 0; t < 8; ++t) {
      const float s = wave_sum(d1 * cst[t]);
      const float d0t = (1.0f / 8192.0f) / (s + kEps);
      d0v[t] = d0t;
      p = fmaf(d0t, cst[t], p);
    }
    __syncthreads();
    lds[wid * 64 + lane] = p;
    __syncthreads();
    if (wid == 0) {
      float bp = 0.0f;
#pragma unroll
      for (int w = 0; w < 16; ++w) bp += lds[w * 64 + lane];
      gpart[buf * (kSinkBlocks * 64) + blk * 64 + lane] = bp;
    }
    grid.sync();
    // every block redundantly reduces all 64 partials in identical order ->
    // bitwise-identical d1/err in all blocks -> uniform loop exit
    const float* gp = gpart + buf * (kSinkBlocks * 64);
    float s2 = 0.0f;
#pragma unroll
    for (int i = 0; i < 4; ++i) s2 += gp[(wid * 4 + i) * 64 + lane];
    lds[wid * 64 + lane] = s2;
    __syncthreads();
    float colsum = 0.0f;
#pragma unroll
    for (int w = 0; w < 16; ++w) colsum += lds[w * 64 + lane];
    const float d1n = (1.0f / 64.0f) / (colsum + kEps);
    const float err = wave_sum(fabsf(d1 - d1n)) * (1.0f / 64.0f);
    d1 = d1n;
    buf ^= 1;
    if (err <= kTol) break;
  }

  // top-2 of d1*cost*d0 + softmax scores
#pragma unroll
  for (int t = 0; t < 8; ++t) {
    const float lgv = lg[t];
    float m = lgv;
#pragma unroll
    for (int o = 32; o; o >>= 1) m = fmaxf(m, __shfl_xor(m, o, 64));
    const float ex = expf(lgv - m);
    const float den = wave_sum(ex);
    const float prob = ex / den;

    const float v = (d1 * cst[t]) * d0v[t];
    float v1 = v;
    int i1 = lane;
#pragma unroll
    for (int o = 32; o; o >>= 1) {
      const float ov = __shfl_xor(v1, o, 64);
      const int oi = __shfl_xor(i1, o, 64);
      if (ov > v1 || (ov == v1 && oi < i1)) { v1 = ov; i1 = oi; }
    }
    float v2 = (lane == i1) ? -INFINITY : v;
    int i2 = lane;
#pragma unroll
    for (int o = 32; o; o >>= 1) {
      const float ov = __shfl_xor(v2, o, 64);
      const int oi = __shfl_xor(i2, o, 64);
      if (ov > v2 || (ov == v2 && oi < i2)) { v2 = ov; i2 = oi; }
    }
    const float p1 = __shfl(prob, i1, 64);
    const float p2 = __shfl(prob, i2, 64);
    if (lane == 0) {
      const int row = t0 + t;
      out[row * 2 + 0] = p1;
      out[row * 2 + 1] = p2;
      out[2 * kTokens + row * 2 + 0] = (float)i1;
      out[2 * kTokens + row * 2 + 1] = (float)i2;
    }
  }
}

// ---------- fallback: round-1 monolithic cooperative kernel ----------
__global__ void __launch_bounds__(256, 1)
sinkhorn_router(const float* __restrict__ X, const float* __restrict__ W,
                float* __restrict__ out, float* __restrict__ ws) {
  cg::grid_group grid = cg::this_grid();
  const int tid = threadIdx.x;
  const int lane = tid & 63;
  const int wid = __builtin_amdgcn_readfirstlane(tid >> 6);
  const int blk = blockIdx.x;

  float4* wtp = reinterpret_cast<float4*>(ws);
  float* gpart = ws + kWtpFloats;
  __shared__ float lds[256];

  {
    const int j = blk * 256 + tid;
    const int e = j & 63;
    const int k4 = j >> 6;
    wtp[j] = *reinterpret_cast<const float4*>(W + (size_t)e * kHS + 4 * (size_t)k4);
  }
  grid.sync();

  const int t0 = blk * 32 + wid * 8;
  const float* xb = X + (size_t)t0 * kHS;
  float lg[8];
#pragma unroll
  for (int t = 0; t < 8; ++t) lg[t] = 0.0f;

#pragma unroll 2
  for (int k4 = 0; k4 < kHS / 4; ++k4) {
    const float4 w = wtp[k4 * 64 + lane];
#pragma unroll
    for (int t = 0; t < 8; ++t) {
      const float* xr = xb + (size_t)t * kHS + 4 * (size_t)k4;
      float a = lg[t];
      a = fmaf(xr[0], w.x, a);
      a = fmaf(xr[1], w.y, a);
      a = fmaf(xr[2], w.z, a);
      a = fmaf(xr[3], w.w, a);
      lg[t] = a;
    }
  }

  float cst[8];
#pragma unroll
  for (int t = 0; t < 8; ++t) cst[t] = expf(lg[t]);

  float d1 = 1.0f;
  float d0v[8];
  int buf = 0;
  for (int it = 0; it < kMaxIters; ++it) {
    float p = 0.0f;
#pragma unroll
    for (int t = 0; t < 8; ++t) {
      const float s = wave_sum(d1 * cst[t]);
      const float d0t = (1.0f / 8192.0f) / (s + kEps);
      d0v[t] = d0t;
      p = fmaf(d0t, cst[t], p);
    }
    __syncthreads();
    lds[wid * 64 + lane] = p;
    __syncthreads();
    if (wid == 0) {
      const float bp =
          lds[lane] + lds[64 + lane] + lds[128 + lane] + lds[192 + lane];
      gpart[buf * (256 * 64) + blk * 64 + lane] = bp;
    }
    grid.sync();
    const float* gp = gpart + buf * (256 * 64);
    float s = 0.0f;
#pragma unroll 8
    for (int b = 0; b < 64; ++b) s += gp[(wid * 64 + b) * 64 + lane];
    lds[wid * 64 + lane] = s;
    __syncthreads();
    const float colsum =
        lds[lane] + lds[64 + lane] + lds[128 + lane] + lds[192 + lane];
    const float d1n = (1.0f / 64.0f) / (colsum + kEps);
    const float err = wave_sum(fabsf(d1 - d1n)) * (1.0f / 64.0f);
    d1 = d1n;
    buf ^= 1;
    if (err <= kTol) break;
  }

#pragma unroll
  for (int t = 0; t < 8; ++t) {
    const float lgv = lg[t];
    float m = lgv;
#pragma unroll
    for (int o = 32; o; o >>= 1) m = fmaxf(m, __shfl_xor(m, o, 64));
    const float ex = expf(lgv - m);
    const float den = wave_sum(ex);
    const float prob = ex / den;

    const float v = (d1 * cst[t]) * d0v[t];
    float v1 = v;
    int i1 = lane;
#pragma unroll
    for (int o = 32; o; o >>= 1) {
      const float ov = __shfl_xor(v1, o, 64);
      const int oi = __shfl_xor(i1, o, 64);
      if (ov > v1 || (ov == v1 && oi < i1)) { v1 = ov; i1 = oi; }
    }
    float v2 = (lane == i1) ? -INFINITY : v;
    int i2 = lane;
#pragma unroll
    for (int o = 32; o; o >>= 1) {
      const float ov = __shfl_xor(v2, o, 64);
      const int oi = __shfl_xor(i2, o, 64);
      if (ov > v2 || (ov == v2 && oi < i2)) { v2 = ov; i2 = oi; }
    }
    const float p1 = __shfl(prob, i1, 64);
    const float p2 = __shfl(prob, i2, 64);
    if (lane == 0) {
      const int row = t0 + t;
      out[row * 2 + 0] = p1;
      out[row * 2 + 1] = p2;
      out[2 * kTokens + row * 2 + 0] = (float)i1;
      out[2 * kTokens + row * 2 + 1] = (float)i2;
    }
  }
}

extern "C" void kernel_launch(void* const* d_in, const int* in_sizes, int n_in,
                              void* d_out, int out_size, void* d_ws,
                              size_t ws_size, hipStream_t stream) {
  const float* X = (const float*)d_in[0];
  const float* W = (const float*)d_in[1];
  float* out = (float*)d_out;
  float* ws = (float*)d_ws;

  // pick largest split-K S in {8,4,2,1} that fits ws
  int S = 0;
  for (int cand : {8, 4, 2, 1}) {
    const size_t need = ((size_t)cand * kSliceFloats + kGpartFloats) * 4;
    if (need <= ws_size) { S = cand; break; }
  }

  if (S == 0) {
    void* args[] = {(void*)&X, (void*)&W, (void*)&out, (void*)&ws};
    hipLaunchCooperativeKernel((const void*)sinkhorn_router, dim3(256),
                               dim3(256), args, 0, stream);
    return;
  }

  float* part = ws;
  float* gpart = part + (size_t)S * kSliceFloats;

  const int KS = kHS / S;
  hipLaunchKernelGGL(k_logits, dim3(128 * S), dim3(256), 0, stream, X, W, part,
                     KS);

  const float* partc = part;
  void* args[] = {(void*)&partc, (void*)&S, (void*)&out, (void*)&gpart};
  hipLaunchCooperativeKernel((const void*)k_sinkhorn, dim3(kSinkBlocks),
                             dim3(1024), args, 0, stream);
}

// Round 5
// 279.272 us; speedup vs baseline: 2.2214x; 1.0786x over previous
//
#include <hip/hip_runtime.h>
#include <hip/hip_cooperative_groups.h>
#include <math.h>

namespace cg = cooperative_groups;

namespace {
constexpr int kTokens = 8192;
constexpr int kHS = 4096;
constexpr float kTol = 1e-4f;
constexpr float kEps = 1e-8f;
constexpr int kMaxIters = 1000;
constexpr int kSinkBlocks = 64;  // regular launch; 64 << 256 CUs -> co-resident
// ws layout: [tags: 2*64 uint][pad][gdata: 2*64*64 f32][part: S*8192*64 f32]
constexpr size_t kTagFloats = 128;        // 2*64 uints
constexpr size_t kGdataFloats = 2 * 64 * 64;  // 8192
constexpr size_t kPartOff = kTagFloats + kGdataFloats;  // 8320 floats
constexpr size_t kSliceFloats = (size_t)kTokens * 64;   // 524288
constexpr size_t kWtpFloats = (size_t)(kHS / 4) * 64 * 4;  // fallback only
}  // namespace

__device__ __forceinline__ float wave_sum(float v) {
#pragma unroll
  for (int o = 32; o; o >>= 1) v += __shfl_xor(v, o, 64);
  return v;
}

// ---------- K1: split-K SGEMM logits. grid = 64*S blocks, 128 threads ----------
// Block tile: 128 tokens x 64 experts x KS. Thread tile 8x8 -> LDS bytes/FMA
// halves vs 4x4 (the round-4 LDS-BW wall). BK=32.
__global__ void __launch_bounds__(128, 2)
k_logits(const float* __restrict__ X, const float* __restrict__ W,
         float* __restrict__ part, int KS) {
  __shared__ float xs[32][132];
  __shared__ float wsh[32][68];
  const int tid = threadIdx.x;
  const int tx = tid & 7;    // expert group: 8*tx..8*tx+7
  const int ty = tid >> 3;   // token group: 8*ty..8*ty+7
  const int tb = blockIdx.x & 63;  // token block
  const int s = blockIdx.x >> 6;   // k-slice
  const int t0 = tb * 128;
  const int k0 = s * KS;
  const int cx = tid & 7;   // staging k-chunk (16B)
  const int rx = tid >> 3;  // staging row (16 rows per pass)

  const float* xsrc = X + (size_t)(t0 + rx) * kHS + k0 + 4 * cx;
  const float* wsrc = W + (size_t)rx * kHS + k0 + 4 * cx;

  float acc[8][8];
#pragma unroll
  for (int i = 0; i < 8; ++i)
#pragma unroll
    for (int j = 0; j < 8; ++j) acc[i][j] = 0.0f;

  const int nkt = KS / 32;
  float4 xa[8], wa[4];
#pragma unroll
  for (int p = 0; p < 8; ++p)
    xa[p] = *(const float4*)(xsrc + (size_t)p * 16 * kHS);
#pragma unroll
  for (int p = 0; p < 4; ++p)
    wa[p] = *(const float4*)(wsrc + (size_t)p * 16 * kHS);

  for (int kt = 0; kt < nkt; ++kt) {
    __syncthreads();
#pragma unroll
    for (int p = 0; p < 8; ++p) {
      xs[4 * cx + 0][rx + 16 * p] = xa[p].x;
      xs[4 * cx + 1][rx + 16 * p] = xa[p].y;
      xs[4 * cx + 2][rx + 16 * p] = xa[p].z;
      xs[4 * cx + 3][rx + 16 * p] = xa[p].w;
    }
#pragma unroll
    for (int p = 0; p < 4; ++p) {
      wsh[4 * cx + 0][rx + 16 * p] = wa[p].x;
      wsh[4 * cx + 1][rx + 16 * p] = wa[p].y;
      wsh[4 * cx + 2][rx + 16 * p] = wa[p].z;
      wsh[4 * cx + 3][rx + 16 * p] = wa[p].w;
    }
    __syncthreads();
    if (kt + 1 < nkt) {  // prefetch next tile
      const int ko = (kt + 1) * 32;
#pragma unroll
      for (int p = 0; p < 8; ++p)
        xa[p] = *(const float4*)(xsrc + (size_t)p * 16 * kHS + ko);
#pragma unroll
      for (int p = 0; p < 4; ++p)
        wa[p] = *(const float4*)(wsrc + (size_t)p * 16 * kHS + ko);
    }
#pragma unroll 8
    for (int k = 0; k < 32; ++k) {
      const float4 x0 = *(const float4*)&xs[k][8 * ty];
      const float4 x1 = *(const float4*)&xs[k][8 * ty + 4];
      const float4 w0 = *(const float4*)&wsh[k][8 * tx];
      const float4 w1 = *(const float4*)&wsh[k][8 * tx + 4];
      const float xr[8] = {x0.x, x0.y, x0.z, x0.w, x1.x, x1.y, x1.z, x1.w};
      const float wr[8] = {w0.x, w0.y, w0.z, w0.w, w1.x, w1.y, w1.z, w1.w};
#pragma unroll
      for (int i = 0; i < 8; ++i)
#pragma unroll
        for (int j = 0; j < 8; ++j) acc[i][j] = fmaf(xr[i], wr[j], acc[i][j]);
    }
  }

  float* pb = part + ((size_t)s * kTokens + t0 + 8 * ty) * 64 + 8 * tx;
#pragma unroll
  for (int i = 0; i < 8; ++i) {
    *(float4*)(pb + (size_t)i * 64) =
        make_float4(acc[i][0], acc[i][1], acc[i][2], acc[i][3]);
    *(float4*)(pb + (size_t)i * 64 + 4) =
        make_float4(acc[i][4], acc[i][5], acc[i][6], acc[i][7]);
  }
}

// ---------- K2: sinkhorn + top-2 + softmax, custom tag barrier ----------
// Regular launch, 64 blocks x 1024 threads (co-resident: 64 << 256 CUs).
// Per iter: block publishes its 64 col-partials + generation tag
// (release, agent scope); wave 0 polls all 64 tags; double-buffered slots.
__global__ void __launch_bounds__(1024, 1)
k_sinkhorn(const float* __restrict__ part, int S, float* __restrict__ out,
           unsigned* __restrict__ tags, float* __restrict__ gdata) {
  const int tid = threadIdx.x;
  const int lane = tid & 63;
  const int wid = __builtin_amdgcn_readfirstlane(tid >> 6);  // 0..15
  const int blk = blockIdx.x;                                // 0..63
  __shared__ float lds[1024];

  const int t0 = blk * 128 + wid * 8;
  float lg[8], cst[8];
#pragma unroll
  for (int t = 0; t < 8; ++t) {
    float a = 0.0f;
    for (int s = 0; s < S; ++s)
      a += part[((size_t)s * kTokens + t0 + t) * 64 + lane];
    lg[t] = a;
    cst[t] = expf(a);
  }

  // lane e holds d1[e]
  float d1 = 1.0f;
  float d0v[8];
  int buf = 0;
  for (int it = 0; it < kMaxIters; ++it) {
    float p = 0.0f;
#pragma unroll
    for (int t = 0; t < 8; ++t) {
      const float s = wave_sum(d1 * cst[t]);
      const float d0t = (1.0f / 8192.0f) / (s + kEps);
      d0v[t] = d0t;
      p = fmaf(d0t, cst[t], p);
    }
    __syncthreads();
    lds[wid * 64 + lane] = p;
    __syncthreads();
    const unsigned want = (unsigned)(it + 1);
    if (wid == 0) {
      float bp = 0.0f;
#pragma unroll
      for (int w = 0; w < 16; ++w) bp += lds[w * 64 + lane];
      // publish data then tag (release orders the wave's prior stores)
      __hip_atomic_store(&gdata[((size_t)buf * 64 + blk) * 64 + lane], bp,
                         __ATOMIC_RELAXED, __HIP_MEMORY_SCOPE_AGENT);
      __threadfence();
      if (lane == 0)
        __hip_atomic_store(&tags[buf * 64 + blk], want, __ATOMIC_RELEASE,
                           __HIP_MEMORY_SCOPE_AGENT);
      // poll: lane b waits for block b's tag
      while (__hip_atomic_load(&tags[buf * 64 + lane], __ATOMIC_ACQUIRE,
                               __HIP_MEMORY_SCOPE_AGENT) != want) {
        __builtin_amdgcn_s_sleep(1);
      }
    }
    __syncthreads();
    // every block reduces all 64 partials in identical order ->
    // bitwise-identical d1/err everywhere -> uniform loop exit
    float s2 = 0.0f;
#pragma unroll
    for (int i = 0; i < 4; ++i)
      s2 += __hip_atomic_load(
          &gdata[((size_t)buf * 64 + wid * 4 + i) * 64 + lane],
          __ATOMIC_RELAXED, __HIP_MEMORY_SCOPE_AGENT);
    lds[wid * 64 + lane] = s2;
    __syncthreads();
    float colsum = 0.0f;
#pragma unroll
    for (int w = 0; w < 16; ++w) colsum += lds[w * 64 + lane];
    const float d1n = (1.0f / 64.0f) / (colsum + kEps);
    const float err = wave_sum(fabsf(d1 - d1n)) * (1.0f / 64.0f);
    d1 = d1n;
    buf ^= 1;
    if (err <= kTol) break;
  }

  // top-2 of d1*cost*d0 + softmax scores
#pragma unroll
  for (int t = 0; t < 8; ++t) {
    const float lgv = lg[t];
    float m = lgv;
#pragma unroll
    for (int o = 32; o; o >>= 1) m = fmaxf(m, __shfl_xor(m, o, 64));
    const float ex = expf(lgv - m);
    const float den = wave_sum(ex);
    const float prob = ex / den;

    const float v = (d1 * cst[t]) * d0v[t];
    float v1 = v;
    int i1 = lane;
#pragma unroll
    for (int o = 32; o; o >>= 1) {
      const float ov = __shfl_xor(v1, o, 64);
      const int oi = __shfl_xor(i1, o, 64);
      if (ov > v1 || (ov == v1 && oi < i1)) { v1 = ov; i1 = oi; }
    }
    float v2 = (lane == i1) ? -INFINITY : v;
    int i2 = lane;
#pragma unroll
    for (int o = 32; o; o >>= 1) {
      const float ov = __shfl_xor(v2, o, 64);
      const int oi = __shfl_xor(i2, o, 64);
      if (ov > v2 || (ov == v2 && oi < i2)) { v2 = ov; i2 = oi; }
    }
    const float p1 = __shfl(prob, i1, 64);
    const float p2 = __shfl(prob, i2, 64);
    if (lane == 0) {
      const int row = t0 + t;
      out[row * 2 + 0] = p1;
      out[row * 2 + 1] = p2;
      out[2 * kTokens + row * 2 + 0] = (float)i1;
      out[2 * kTokens + row * 2 + 1] = (float)i2;
    }
  }
}

// ---------- fallback: round-1 monolithic cooperative kernel ----------
__global__ void __launch_bounds__(256, 1)
sinkhorn_router(const float* __restrict__ X, const float* __restrict__ W,
                float* __restrict__ out, float* __restrict__ ws) {
  cg::grid_group grid = cg::this_grid();
  const int tid = threadIdx.x;
  const int lane = tid & 63;
  const int wid = __builtin_amdgcn_readfirstlane(tid >> 6);
  const int blk = blockIdx.x;

  float4* wtp = reinterpret_cast<float4*>(ws);
  float* gpart = ws + kWtpFloats;
  __shared__ float lds[256];

  {
    const int j = blk * 256 + tid;
    const int e = j & 63;
    const int k4 = j >> 6;
    wtp[j] = *reinterpret_cast<const float4*>(W + (size_t)e * kHS + 4 * (size_t)k4);
  }
  grid.sync();

  const int t0 = blk * 32 + wid * 8;
  const float* xb = X + (size_t)t0 * kHS;
  float lg[8];
#pragma unroll
  for (int t = 0; t < 8; ++t) lg[t] = 0.0f;

#pragma unroll 2
  for (int k4 = 0; k4 < kHS / 4; ++k4) {
    const float4 w = wtp[k4 * 64 + lane];
#pragma unroll
    for (int t = 0; t < 8; ++t) {
      const float* xr = xb + (size_t)t * kHS + 4 * (size_t)k4;
      float a = lg[t];
      a = fmaf(xr[0], w.x, a);
      a = fmaf(xr[1], w.y, a);
      a = fmaf(xr[2], w.z, a);
      a = fmaf(xr[3], w.w, a);
      lg[t] = a;
    }
  }

  float cst[8];
#pragma unroll
  for (int t = 0; t < 8; ++t) cst[t] = expf(lg[t]);

  float d1 = 1.0f;
  float d0v[8];
  int buf = 0;
  for (int it = 0; it < kMaxIters; ++it) {
    float p = 0.0f;
#pragma unroll
    for (int t = 0; t < 8; ++t) {
      const float s = wave_sum(d1 * cst[t]);
      const float d0t = (1.0f / 8192.0f) / (s + kEps);
      d0v[t] = d0t;
      p = fmaf(d0t, cst[t], p);
    }
    __syncthreads();
    lds[wid * 64 + lane] = p;
    __syncthreads();
    if (wid == 0) {
      const float bp =
          lds[lane] + lds[64 + lane] + lds[128 + lane] + lds[192 + lane];
      gpart[buf * (256 * 64) + blk * 64 + lane] = bp;
    }
    grid.sync();
    const float* gp = gpart + buf * (256 * 64);
    float s = 0.0f;
#pragma unroll 8
    for (int b = 0; b < 64; ++b) s += gp[(wid * 64 + b) * 64 + lane];
    lds[wid * 64 + lane] = s;
    __syncthreads();
    const float colsum =
        lds[lane] + lds[64 + lane] + lds[128 + lane] + lds[192 + lane];
    const float d1n = (1.0f / 64.0f) / (colsum + kEps);
    const float err = wave_sum(fabsf(d1 - d1n)) * (1.0f / 64.0f);
    d1 = d1n;
    buf ^= 1;
    if (err <= kTol) break;
  }

#pragma unroll
  for (int t = 0; t < 8; ++t) {
    const float lgv = lg[t];
    float m = lgv;
#pragma unroll
    for (int o = 32; o; o >>= 1) m = fmaxf(m, __shfl_xor(m, o, 64));
    const float ex = expf(lgv - m);
    const float den = wave_sum(ex);
    const float prob = ex / den;

    const float v = (d1 * cst[t]) * d0v[t];
    float v1 = v;
    int i1 = lane;
#pragma unroll
    for (int o = 32; o; o >>= 1) {
      const float ov = __shfl_xor(v1, o, 64);
      const int oi = __shfl_xor(i1, o, 64);
      if (ov > v1 || (ov == v1 && oi < i1)) { v1 = ov; i1 = oi; }
    }
    float v2 = (lane == i1) ? -INFINITY : v;
    int i2 = lane;
#pragma unroll
    for (int o = 32; o; o >>= 1) {
      const float ov = __shfl_xor(v2, o, 64);
      const int oi = __shfl_xor(i2, o, 64);
      if (ov > v2 || (ov == v2 && oi < i2)) { v2 = ov; i2 = oi; }
    }
    const float p1 = __shfl(prob, i1, 64);
    const float p2 = __shfl(prob, i2, 64);
    if (lane == 0) {
      const int row = t0 + t;
      out[row * 2 + 0] = p1;
      out[row * 2 + 1] = p2;
      out[2 * kTokens + row * 2 + 0] = (float)i1;
      out[2 * kTokens + row * 2 + 1] = (float)i2;
    }
  }
}

extern "C" void kernel_launch(void* const* d_in, const int* in_sizes, int n_in,
                              void* d_out, int out_size, void* d_ws,
                              size_t ws_size, hipStream_t stream) {
  const float* X = (const float*)d_in[0];
  const float* W = (const float*)d_in[1];
  float* out = (float*)d_out;
  float* ws = (float*)d_ws;

  // pick largest split-K S in {16,8,4,2,1} that fits ws
  int S = 0;
  for (int cand : {16, 8, 4, 2, 1}) {
    const size_t need = (kPartOff + (size_t)cand * kSliceFloats) * 4;
    if (need <= ws_size) { S = cand; break; }
  }

  if (S == 0) {
    void* args[] = {(void*)&X, (void*)&W, (void*)&out, (void*)&ws};
    hipLaunchCooperativeKernel((const void*)sinkhorn_router, dim3(256),
                               dim3(256), args, 0, stream);
    return;
  }

  unsigned* tags = reinterpret_cast<unsigned*>(ws);
  float* gdata = ws + kTagFloats;
  float* part = ws + kPartOff;

  const int KS = kHS / S;
  hipLaunchKernelGGL(k_logits, dim3(64 * S), dim3(128), 0, stream, X, W, part,
                     KS);
  hipLaunchKernelGGL(k_sinkhorn, dim3(kSinkBlocks), dim3(1024), 0, stream,
                     part, S, out, tags, gdata);
}